// Round 6
// baseline (187.330 us; speedup 1.0000x reference)
//
#include <hip/hip_runtime.h>

#define IN_CH 128
#define OUT_CH 64
#define TN 64            // nodes per gemm block
#define XS_STRIDE 132    // padded x-tile stride  (bank (4n+k)%32 -> 2-way, free)
#define WS_STRIDE 129    // padded W staging stride (bank (o+k)%32 -> conflict-free transpose)
#define SLOT_CAP 64      // per-node direct-bin capacity; Poisson(16) => P(d>64) ~ 0

// fp32 -> bf16 (RNE)
__device__ __forceinline__ unsigned f2bf(float f) {
    unsigned u = __float_as_uint(f);
    return (u + 0x7FFFu + ((u >> 16) & 1u)) >> 16;
}

// ---------------- fused: zero cnt + spillCount + detect int64 indices ----------------
__global__ __launch_bounds__(256) void k_init(const int* __restrict__ ei,
                                              int* __restrict__ cnt,
                                              int* __restrict__ spillCount,
                                              int* __restrict__ flag, int nNodes) {
    int i = blockIdx.x * 256 + threadIdx.x;
    if (i < nNodes) cnt[i] = 0;
    if (blockIdx.x == 0 && threadIdx.x == 0) {
        int is64 = 1;
#pragma unroll
        for (int j = 0; j < 16; ++j)
            if (ei[2 * j + 1] != 0) is64 = 0;
        *flag = is64;
        *spillCount = 0;
    }
}

// ---------------- convert + direct bin: slots[dst*64 + rank] = src ----------------
__global__ __launch_bounds__(256) void k_convert(const int* __restrict__ ei,
                                                 int* __restrict__ cnt,
                                                 int* __restrict__ slots,
                                                 uint2* __restrict__ spill,
                                                 int* __restrict__ spillCount,
                                                 int nEdges, int nNodes,
                                                 const int* __restrict__ flag64) {
    int e = blockIdx.x * 256 + threadIdx.x;
    if (e >= nEdges) return;
    int src, dst;
    if (*flag64) {
        const long long* e64 = (const long long*)ei;
        src = (int)e64[e];
        dst = (int)e64[nEdges + e];
    } else {
        src = ei[e];
        dst = ei[nEdges + e];
    }
    if ((unsigned)src >= (unsigned)nNodes) src = 0;
    if ((unsigned)dst >= (unsigned)nNodes) dst = 0;
    int rank = atomicAdd(&cnt[dst], 1);
    if (rank < SLOT_CAP) {
        slots[dst * SLOT_CAP + rank] = src;
    } else {
        int sp = atomicAdd(spillCount, 1);
        if (sp < nEdges) spill[sp] = make_uint2((unsigned)src, (unsigned)dst);
    }
}

// ---------------- h = x @ W^T, h stored as bf16 pairs ----------------
__device__ __forceinline__ void fma4(float4& acc, float s, const float4& wv) {
    acc.x += s * wv.x;
    acc.y += s * wv.y;
    acc.z += s * wv.z;
    acc.w += s * wv.w;
}

__global__ __launch_bounds__(256) void k_gemm(const float* __restrict__ x,
                                              const float* __restrict__ W,
                                              unsigned* __restrict__ h16,  // [node][32] bf16x2
                                              int nNodes) {
    __shared__ float smem[TN * XS_STRIDE + IN_CH * OUT_CH];
    float* u  = smem;                   // W staging (str 129) then x tile (str 132)
    float* wt = smem + TN * XS_STRIDE;  // wt[k][o]

    int tid = threadIdx.x;
    int nodeBase = blockIdx.x * TN;

    {
        const float4* W4 = (const float4*)W;
        for (int i = tid; i < IN_CH * OUT_CH / 4; i += 256) {
            float4 v = W4[i];
            int o = i >> 5;
            int k = (i & 31) * 4;
            float* d = u + o * WS_STRIDE + k;
            d[0] = v.x; d[1] = v.y; d[2] = v.z; d[3] = v.w;
        }
    }
    __syncthreads();
    {
        int o = tid & 63;
        int k0 = (tid >> 6) * 32;
#pragma unroll 8
        for (int k = k0; k < k0 + 32; ++k)
            wt[k * OUT_CH + o] = u[o * WS_STRIDE + k];
    }
    __syncthreads();
    {
        int remRows = nNodes - nodeBase;
        if (remRows > TN) remRows = TN;
        const float4* X4 = (const float4*)(x + (size_t)nodeBase * IN_CH);
        for (int i = tid; i < TN * IN_CH / 4; i += 256) {
            int r = i >> 5;
            int k = (i & 31) * 4;
            float4 v = make_float4(0.f, 0.f, 0.f, 0.f);
            if (r < remRows) v = X4[i];
            *(float4*)(u + r * XS_STRIDE + k) = v;
        }
    }
    __syncthreads();

    int tx = tid & 15;
    int ty = tid >> 4;

    float4 acc[4];
#pragma unroll
    for (int i = 0; i < 4; ++i) acc[i] = make_float4(0.f, 0.f, 0.f, 0.f);

    const float* wcol = wt + tx * 4;
#pragma unroll 4
    for (int k = 0; k < IN_CH; k += 4) {
        float4 w0 = *(const float4*)(wcol + (k + 0) * OUT_CH);
        float4 w1 = *(const float4*)(wcol + (k + 1) * OUT_CH);
        float4 w2 = *(const float4*)(wcol + (k + 2) * OUT_CH);
        float4 w3 = *(const float4*)(wcol + (k + 3) * OUT_CH);
#pragma unroll
        for (int i = 0; i < 4; ++i) {
            float4 a = *(const float4*)(u + (ty * 4 + i) * XS_STRIDE + k);
            fma4(acc[i], a.x, w0);
            fma4(acc[i], a.y, w1);
            fma4(acc[i], a.z, w2);
            fma4(acc[i], a.w, w3);
        }
    }

#pragma unroll
    for (int i = 0; i < 4; ++i) {
        int n = nodeBase + ty * 4 + i;
        if (n < nNodes) {
            uint2 pk;
            pk.x = f2bf(acc[i].x) | (f2bf(acc[i].y) << 16);
            pk.y = f2bf(acc[i].z) | (f2bf(acc[i].w) << 16);
            *(uint2*)(h16 + (size_t)n * 32 + tx * 2) = pk;
        }
    }
}

// ---------------- gather-reduce: one wave per node, 2 halves x 1 edge/iter step 2 ----------------
__global__ __launch_bounds__(256) void k_gather(const int* __restrict__ cnt,
                                                const int* __restrict__ slots,
                                                const unsigned* __restrict__ h16,
                                                const float* __restrict__ bias,
                                                float* __restrict__ out, int nNodes) {
    int tid = blockIdx.x * 256 + threadIdx.x;
    int node = tid >> 6;
    if (node >= nNodes) return;
    int lane = tid & 63;
    int half = lane >> 5;
    int cp   = lane & 31;

    int d = cnt[node];
    if (d > SLOT_CAP) d = SLOT_CAP;
    int b = node * SLOT_CAP;
    int e = b + d;

    float2 acc = {0.f, 0.f};
    int i = b + half;
    for (; i + 2 < e; i += 4) {  // this half: edges i and i+2
        int s0 = slots[i];
        int s1 = slots[i + 2];
        unsigned v0 = h16[(size_t)s0 * 32 + cp];
        unsigned v1 = h16[(size_t)s1 * 32 + cp];
        acc.x += __uint_as_float(v0 << 16);
        acc.y += __uint_as_float(v0 & 0xFFFF0000u);
        acc.x += __uint_as_float(v1 << 16);
        acc.y += __uint_as_float(v1 & 0xFFFF0000u);
    }
    if (i < e) {
        int s = slots[i];
        unsigned v = h16[(size_t)s * 32 + cp];
        acc.x += __uint_as_float(v << 16);
        acc.y += __uint_as_float(v & 0xFFFF0000u);
    }

    acc.x += __shfl_down(acc.x, 32, 64);
    acc.y += __shfl_down(acc.y, 32, 64);
    if (half == 0) {
        float2 bv = *(const float2*)(bias + cp * 2);
        float2 o;
        o.x = acc.x + bv.x;
        o.y = acc.y + bv.y;
        *(float2*)(out + (size_t)node * OUT_CH + cp * 2) = o;
    }
}

// ---------------- spill fixup (normally 0 iterations) ----------------
__global__ __launch_bounds__(256) void k_spill(const uint2* __restrict__ spill,
                                               const int* __restrict__ spillCount,
                                               const unsigned* __restrict__ h16,
                                               float* __restrict__ out, int nEdges) {
    int n = *spillCount;
    if (n > nEdges) n = nEdges;
    long long total = (long long)n * 32;
    for (long long t = blockIdx.x * 256 + threadIdx.x; t < total; t += (long long)gridDim.x * 256) {
        int e = (int)(t >> 5);
        int cp = (int)(t & 31);
        uint2 sd = spill[e];
        unsigned v = h16[(size_t)sd.x * 32 + cp];
        float* o = out + (size_t)sd.y * OUT_CH + cp * 2;
        unsafeAtomicAdd(o + 0, __uint_as_float(v << 16));
        unsafeAtomicAdd(o + 1, __uint_as_float(v & 0xFFFF0000u));
    }
}

extern "C" void kernel_launch(void* const* d_in, const int* in_sizes, int n_in,
                              void* d_out, int out_size, void* d_ws, size_t ws_size,
                              hipStream_t stream) {
    const float* x    = (const float*)d_in[0];
    const int*   ei   = (const int*)d_in[1];
    const float* W    = (const float*)d_in[2];
    const float* bias = (const float*)d_in[3];
    float* out = (float*)d_out;

    int nNodes = in_sizes[0] / IN_CH;   // 50000
    int nEdges = in_sizes[1] / 2;       // 800000

    char* p = (char*)d_ws;
    auto alloc = [&](size_t bytes) {
        char* r = p;
        p += (bytes + 255) & ~(size_t)255;
        return r;
    };
    unsigned* h16        = (unsigned*)alloc((size_t)nNodes * 32 * sizeof(unsigned));   // 6.4 MB
    int*      slots      = (int*)alloc((size_t)nNodes * SLOT_CAP * sizeof(int));       // 12.8 MB
    uint2*    spill      = (uint2*)alloc((size_t)nEdges * sizeof(uint2));              // 6.4 MB
    int*      cnt        = (int*)alloc((size_t)nNodes * sizeof(int));
    int*      spillCount = (int*)alloc(sizeof(int));
    int*      flag       = (int*)alloc(sizeof(int));

    int nBlk = (nNodes + 255) / 256;

    k_init<<<nBlk, 256, 0, stream>>>(ei, cnt, spillCount, flag, nNodes);
    k_convert<<<(nEdges + 255) / 256, 256, 0, stream>>>(ei, cnt, slots, spill, spillCount, nEdges, nNodes, flag);
    k_gemm<<<(nNodes + TN - 1) / TN, 256, 0, stream>>>(x, W, h16, nNodes);
    k_gather<<<(nNodes * OUT_CH + 255) / 256, 256, 0, stream>>>(cnt, slots, h16, bias, out, nNodes);
    k_spill<<<64, 256, 0, stream>>>(spill, spillCount, h16, out, nEdges);
}